// Round 1
// baseline (415.287 us; speedup 1.0000x reference)
//
#include <hip/hip_runtime.h>

#define M_DIM 4096
#define K_DIM 16384
#define N_DIM 256

typedef __bf16 bf16x8 __attribute__((ext_vector_type(8)));
typedef float f32x4 __attribute__((ext_vector_type(4)));
typedef unsigned short us4 __attribute__((ext_vector_type(4)));
typedef unsigned short us8 __attribute__((ext_vector_type(8)));

__device__ __forceinline__ unsigned short f2bf(float f) {
  // round-to-nearest-even fp32 -> bf16 bits
  unsigned int u = __float_as_uint(f);
  u += 0x7fffu + ((u >> 16) & 1u);
  return (unsigned short)(u >> 16);
}

// ---------------- W transpose + convert: Wt[n][k] = bf16(W[k][n]) ----------------
__global__ __launch_bounds__(256) void wt_kernel(const float* __restrict__ W,
                                                 unsigned short* __restrict__ Wt) {
  __shared__ float tile[64][65];  // +1 pad breaks bank conflicts on transposed reads
  const int k0 = blockIdx.x * 64, n0 = blockIdx.y * 64;
  const int t = threadIdx.x;
#pragma unroll
  for (int r = 0; r < 4; ++r) {
    int idx4 = r * 256 + t;
    int kr = idx4 >> 4, c4 = idx4 & 15;
    f32x4 v = *(const f32x4*)(W + (size_t)(k0 + kr) * N_DIM + n0 + c4 * 4);
#pragma unroll
    for (int j = 0; j < 4; ++j) tile[kr][c4 * 4 + j] = v[j];
  }
  __syncthreads();
#pragma unroll
  for (int r = 0; r < 4; ++r) {
    int nr = (t >> 4) + r * 16, k4 = t & 15;  // lanes walk k -> coalesced global store
    us4 o;
#pragma unroll
    for (int j = 0; j < 4; ++j) o[j] = f2bf(tile[k4 * 4 + j][nr]);
    *(us4*)(Wt + (size_t)(n0 + nr) * K_DIM + k0 + k4 * 4) = o;
  }
}

// ---------------- Main MFMA GEMM: partial[s] = x[:, kslice_s] @ W[kslice_s, :] ----------------
// BM=128, BN=256 (full O -> x fetched exactly once), BK=64, 512 threads = 8 waves,
// each wave owns a 64x64 subtile = 4x4 tiles of mfma_f32_16x16x32_bf16.
__global__ __launch_bounds__(512) void gemm_kernel(const float* __restrict__ x,
                                                   const unsigned short* __restrict__ Wt,
                                                   unsigned short* __restrict__ part,
                                                   int kslice) {
  // A: [128][68] bf16, pad 68 -> b64 frag reads land on 8+ distinct bank starts (~free)
  __shared__ unsigned short As[128 * 68];
  // B: 8-row interleaved layout, exact lane order of global_load_lds (no pad allowed):
  //   elem(n,k) at ushort idx = (n>>3)*512 + (k>>3)*64 + (n&7)*8 + (k&7)
  __shared__ unsigned short Bs[256 * 64];

  const int t = threadIdx.x;
  const int l = t & 63;
  const int w = t >> 6;
  const int wm = w >> 2, wn = w & 3;
  const int la = l & 15, q = l >> 4;
  const int m0 = blockIdx.x * 128;
  const int kbase = blockIdx.y * kslice;

  f32x4 acc[4][4];
  const f32x4 zero = {0.f, 0.f, 0.f, 0.f};
#pragma unroll
  for (int i = 0; i < 4; ++i)
#pragma unroll
    for (int j = 0; j < 4; ++j) acc[i][j] = zero;

  const int niter = kslice / 64;
  for (int it = 0; it < niter; ++it) {
    const int k0 = kbase + it * 64;

    // ---- stage B: 4 global_load_lds (16B/lane) per wave; issue first to get in flight ----
#pragma unroll
    for (int c = 0; c < 4; ++c) {
      int nb = w * 32 + c * 8;  // 8 n-rows x 64 k per instruction = 1024B contiguous LDS
      const unsigned short* g = Wt + (size_t)(nb + (l & 7)) * K_DIM + k0 + ((l >> 3) * 8);
      unsigned short* lp = &Bs[nb * 64];  // wave-uniform LDS base
      __builtin_amdgcn_global_load_lds((const __attribute__((address_space(1))) void*)g,
                                       (__attribute__((address_space(3))) void*)lp, 16, 0, 0);
    }

    // ---- stage A: fp32 float4 loads, convert to bf16, ds_write_b64 ----
#pragma unroll
    for (int r = 0; r < 4; ++r) {
      int idx4 = r * 512 + t;
      int row = idx4 >> 4, c4 = idx4 & 15;  // 16 lanes cover one 256B row segment
      f32x4 v = *(const f32x4*)(x + (size_t)(m0 + row) * K_DIM + k0 + c4 * 4);
      us4 o;
      o[0] = f2bf(v[0]); o[1] = f2bf(v[1]); o[2] = f2bf(v[2]); o[3] = f2bf(v[3]);
      *(us4*)(&As[row * 68 + c4 * 4]) = o;
    }
    __syncthreads();

    // ---- fragments + 32 MFMAs per wave ----
#pragma unroll
    for (int ks = 0; ks < 2; ++ks) {
      const int kb = ks * 32 + q * 8;
      union Frag { bf16x8 v; us4 h[2]; us8 o; };
      Frag a[4], b[4];
#pragma unroll
      for (int i = 0; i < 4; ++i) {
        int ml = wm * 64 + i * 16 + la;
        int off = ml * 68 + kb;
        a[i].h[0] = *(const us4*)(&As[off]);
        a[i].h[1] = *(const us4*)(&As[off + 4]);
      }
#pragma unroll
      for (int j = 0; j < 4; ++j) {
        int n = wn * 64 + j * 16 + la;
        int off = (n >> 3) * 512 + (kb >> 3) * 64 + (n & 7) * 8;
        b[j].o = *(const us8*)(&Bs[off]);
      }
#pragma unroll
      for (int i = 0; i < 4; ++i)
#pragma unroll
        for (int j = 0; j < 4; ++j)
          acc[i][j] = __builtin_amdgcn_mfma_f32_16x16x32_bf16(a[i].v, b[j].v, acc[i][j], 0, 0, 0);
    }
    __syncthreads();
  }

  // ---- epilogue: bf16 partials (C/D layout: col=lane&15, row=quad*4+reg) ----
  unsigned short* pbase = part + (size_t)blockIdx.y * ((size_t)M_DIM * N_DIM);
#pragma unroll
  for (int i = 0; i < 4; ++i) {
    int r0 = m0 + wm * 64 + i * 16 + q * 4;
#pragma unroll
    for (int j = 0; j < 4; ++j) {
      int c = wn * 64 + j * 16 + la;
#pragma unroll
      for (int r = 0; r < 4; ++r)
        pbase[(size_t)(r0 + r) * N_DIM + c] = f2bf(acc[i][j][r]);
    }
  }
}

// ---------------- reduce partials + exact fp32 bit-flip correction + bias ----------------
__global__ __launch_bounds__(256) void reduce_kernel(const unsigned short* __restrict__ part,
                                                     int S,
                                                     const float* __restrict__ x,
                                                     const float* __restrict__ W,
                                                     const float* __restrict__ bvec,
                                                     const float* __restrict__ coeffp,
                                                     const int* __restrict__ idx,
                                                     const int* __restrict__ bp,
                                                     float* __restrict__ out) {
  const int row = blockIdx.x;
  const int o = threadIdx.x;
  const int iv = idx[row];
  const float g = x[(size_t)row * K_DIM + iv];
  const int bits = __float_as_int(g) ^ (1 << bp[row]);
  const float upd = __int_as_float(bits) - g;  // swap_sim(g) - g, exact fp32
  const float coeff = coeffp[0];
  const size_t off = (size_t)row * N_DIM + o;
  float sum = 0.f;
  for (int s = 0; s < S; ++s)
    sum += __uint_as_float(((unsigned int)part[(size_t)s * ((size_t)M_DIM * N_DIM) + off]) << 16);
  out[off] = sum + coeff * upd * W[(size_t)iv * N_DIM + o] + bvec[o];
}

extern "C" void kernel_launch(void* const* d_in, const int* in_sizes, int n_in,
                              void* d_out, int out_size, void* d_ws, size_t ws_size,
                              hipStream_t stream) {
  const float* x = (const float*)d_in[0];
  const float* W = (const float*)d_in[1];
  const float* b = (const float*)d_in[2];
  const float* coeff = (const float*)d_in[3];
  const int* idx = (const int*)d_in[4];
  const int* bp = (const int*)d_in[5];
  float* out = (float*)d_out;

  unsigned short* Wt = (unsigned short*)d_ws;
  const size_t wt_bytes = (size_t)K_DIM * N_DIM * 2;  // 8 MiB
  // split-K factor: partials are bf16, 2 MiB each; shrink if ws is small
  int S = 8;
  while (S > 1 && wt_bytes + (size_t)S * M_DIM * N_DIM * 2 > ws_size) S >>= 1;
  unsigned short* part = (unsigned short*)((char*)d_ws + wt_bytes);

  hipLaunchKernelGGL(wt_kernel, dim3(K_DIM / 64, N_DIM / 64), dim3(256), 0, stream, W, Wt);
  hipLaunchKernelGGL(gemm_kernel, dim3(M_DIM / 128, S), dim3(512), 0, stream,
                     x, Wt, part, K_DIM / S);
  hipLaunchKernelGGL(reduce_kernel, dim3(M_DIM), dim3(256), 0, stream,
                     part, S, x, W, b, coeff, idx, bp, out);
}